// Round 8
// baseline (342.706 us; speedup 1.0000x reference)
//
#include <hip/hip_runtime.h>
#include <cstdint>
#include <cstddef>

// ---------------------------------------------------------------------------
// SpatialGRU 32x32, B=64, U=64, C=64. Persistent: 32 rows x 4 batch-tiles
// (bid = row*4+bt). Flag-free handoff (packed 2xf16 dwords, LSB=1 validity;
// 0xAA poison fails). R8: wave-specialized staging —
//   wave 7  : [B] validates+stages hT(j+1) from SPECULATIVE loads issued in
//             [C](j-1) -> poll latency fully overlapped with compute.
//   waves0-3: [C] stage x(j+1) (regs->LDS), prefetch x(j+2).
//   waves0-6: [B] GEMM1 (+fused sigmoid on 0-2, z->Gt on 3-6).
//   waves4-7: [C] GEMM2 full-K n-split + epilogue + handoff store.
// hbuf consumer-contiguous [pair][unit] (one 256B coalesced poll per wave).
// Gt transposed (stride 17) kills the 32-way epilogue bank conflict.
// hT parity-double-buffered in qf and qs32. 2 syncthreads per cell.
// ---------------------------------------------------------------------------

#define LDIM   32
#define NBT    4
#define BT     16
#define TPB    512

typedef _Float16 f16;
typedef _Float16 f16x8 __attribute__((ext_vector_type(8)));
typedef float    f32x4 __attribute__((ext_vector_type(4)));

#define LD_AGENT(p)   __hip_atomic_load((p), __ATOMIC_RELAXED, __HIP_MEMORY_SCOPE_AGENT)
#define ST_AGENT(p,v) __hip_atomic_store((p), (v), __ATOMIC_RELAXED, __HIP_MEMORY_SCOPE_AGENT)

__global__ __launch_bounds__(TPB, 2) void spatial_gru_kernel(
    const float* __restrict__ x,     // (B, C, 32, 32)
    const float* __restrict__ W,     // (256, 448)
    const float* __restrict__ Urec,  // (192, 64)
    const float* __restrict__ bias,  // (512,)
    const float* __restrict__ Wij,   // (64, 64)
    float* __restrict__ out,         // (B, U)
    uint32_t* __restrict__ hbuf)     // (32,32,NBT)[pair 0:8][unit 0:64] dwords
{
    const int bid = blockIdx.x;
    const int row = bid >> 2, bt = bid & 3, b0 = bt * BT;
    const int t = (int)threadIdx.x, u = t & 63, g = t >> 6;
    const int l15 = t & 15, lq = (t & 63) >> 4;

    // ---- LDS ----
    // qf : GEMM1 A (f16) [b][k]: hT_e 0:64 | hL 64:128 | hD 128:192 |
    //                            s_e 192:256 | s_o 256:320 | hT_o 320:384 (+pad)
    // rf : GEMM2 A (f16) [b][k]: r*{hL,hT,hD} 0:192
    // qs32: fp32 state   [b][c]: hT_e 0:64 | hL 64:128 | hD 128:192 | hT_o 192:256
    // Gt : z logits fp32, TRANSPOSED [n 0:256][b]  (stride 17 -> 2-way banks)
    __shared__ __attribute__((aligned(16))) f16 qf[BT][392];
    __shared__ __attribute__((aligned(16))) f16 rf[BT][200];
    __shared__ float qs32[BT][260];
    __shared__ float Gt[256][17];

    // ---- GEMM1 weights resident (waves 0..6: 64 cols each) ----
    f16x8 wreg[4][8];
    float bias1[4] = {0.f, 0.f, 0.f, 0.f};
    if (g < 7) {
        const int nb = g * 64 + l15;
#pragma unroll
        for (int T = 0; T < 4; ++T) {
            bias1[T] = bias[nb + 16 * T];
#pragma unroll
            for (int s = 0; s < 8; ++s) {
                f16x8 v;
#pragma unroll
                for (int jj = 0; jj < 8; ++jj) {
                    int kk = s * 32 + lq * 8 + jj;
                    v[jj] = (f16)W[(size_t)kk * 448 + nb + 16 * T];
                }
                wreg[T][s] = v;
            }
        }
    }
    // ---- GEMM2 weights: wave (g&3) col-tile, FULL K=256 ----
    f16x8 wreg2[8];
    const int n2 = (g & 3) * 16 + l15;
#pragma unroll
    for (int s = 0; s < 8; ++s) {
        f16x8 v;
#pragma unroll
        for (int jj = 0; jj < 8; ++jj) {
            int kk = s * 32 + lq * 8 + jj;
            float wv = (kk < 192) ? Urec[kk * 64 + n2] : Wij[(kk - 192) * 64 + n2];
            v[jj] = (f16)wv;
        }
        wreg2[s] = v;
    }
    const float bias2 = bias[448 + n2];

    // ---- zero init: qs32 all state cols; qf hT_e, hL, hD, hT_o ----
    for (int idx = t; idx < 256 * BT; idx += TPB) {
        int b = idx & 15, k = idx >> 4;
        qs32[b][k] = 0.f;
        qf[b][(k < 192) ? k : (128 + k)] = (f16)0.f;   // 192:256 -> 320:384
    }
    __syncthreads();

    // ---- prologue staging ----
    const float* xg = x + (size_t)(b0 + g) * 65536 + (size_t)u * 1024 + (size_t)row * 32;
    float xv[4] = {0.f, 0.f, 0.f, 0.f};
    uint32_t wsp[8];
    if (g < 4) {
#pragma unroll
        for (int i = 0; i < 4; ++i)
            qf[g + 4 * i][192 + u] = (f16)xg[(size_t)i * 4 * 65536];     // x(0) -> s_e
#pragma unroll
        for (int i = 0; i < 4; ++i)
            xv[i] = xg[(size_t)i * 4 * 65536 + 1];                       // x(1) regs
    } else if (g == 7 && row > 0) {
        // direct poll+stage cell 0 (batched loads, then fixups)
        const uint32_t* hp0 = hbuf + (((size_t)((row - 1) * LDIM) * NBT + bt) << 9) + u;
        uint32_t w0[8];
#pragma unroll
        for (int p = 0; p < 8; ++p) w0[p] = LD_AGENT(hp0 + (p << 6));
#pragma unroll
        for (int p = 0; p < 8; ++p)
            while ((w0[p] & 0x00010001u) != 0x00010001u) {
                __builtin_amdgcn_s_sleep(1);
                w0[p] = LD_AGENT(hp0 + (p << 6));
            }
#pragma unroll
        for (int p = 0; p < 8; ++p) {
            f16 h0 = __builtin_bit_cast(f16, (uint16_t)(w0[p] & 0xFFFFu));
            f16 h1 = __builtin_bit_cast(f16, (uint16_t)(w0[p] >> 16));
            qf[2 * p][u] = h0;           qf[2 * p + 1][u] = h1;          // hT_e
            qs32[2 * p][u] = (float)h0;  qs32[2 * p + 1][u] = (float)h1;
        }
        // speculative loads for cell 1
        const uint32_t* hp1 = hbuf + (((size_t)((row - 1) * LDIM + 1) * NBT + bt) << 9) + u;
#pragma unroll
        for (int p = 0; p < 8; ++p) wsp[p] = LD_AGENT(hp1 + (p << 6));
    }

    for (int j = 0; j < LDIM; ++j) {
        const int par    = j & 1;
        const int hTq    = par ? 320 : 0;    // qf hT base, cell j
        const int sq     = par ? 256 : 192;  // qf s base, cell j
        const int hT32   = par ? 192 : 0;    // qs32 hT base, cell j
        const int hTq_n  = par ? 0 : 320;    // cell j+1
        const int sq_n   = par ? 192 : 256;
        const int hT32_n = par ? 0 : 192;

        __syncthreads();   // s1 — staging of cell j complete

        // ---- [B] ----
        if (g < 7) {
            f32x4 acc[4];
#pragma unroll
            for (int T = 0; T < 4; ++T)
                acc[T] = (f32x4){bias1[T], bias1[T], bias1[T], bias1[T]};
#pragma unroll
            for (int s = 0; s < 8; ++s) {
                const int off = (s < 2) ? hTq + 32 * s : (s < 6) ? 32 * s : sq + 32 * (s - 6);
                f16x8 a = *(const f16x8*)&qf[l15][off + lq * 8];
#pragma unroll
                for (int T = 0; T < 4; ++T)
                    acc[T] = __builtin_amdgcn_mfma_f32_16x16x32_f16(a, wreg[T][s], acc[T], 0, 0, 0);
            }
            if (g < 3) {
                // rf k: 0:64 r*hL | 64:128 r*hT(par) | 128:192 r*hD
                const int colbase = (g == 0) ? 64 : (g == 1) ? hT32 : 128;
#pragma unroll
                for (int T = 0; T < 4; ++T)
#pragma unroll
                    for (int r = 0; r < 4; ++r) {
                        float rr = 1.f / (1.f + __expf(-acc[T][r]));
                        int b = lq * 4 + r;
                        rf[b][g * 64 + T * 16 + l15] = (f16)(rr * qs32[b][colbase + T * 16 + l15]);
                    }
            } else {
                const int zb = (g - 3) * 64;
#pragma unroll
                for (int T = 0; T < 4; ++T)
#pragma unroll
                    for (int r = 0; r < 4; ++r)
                        Gt[zb + T * 16 + l15][lq * 4 + r] = acc[T][r];
            }
        } else if (row > 0 && j < LDIM - 1) {
            // wave 7: validate spec, repoll stragglers, stage hT(j+1)
            const uint32_t* hp = hbuf + (((size_t)((row - 1) * LDIM + (j + 1)) * NBT + bt) << 9) + u;
#pragma unroll
            for (int p = 0; p < 8; ++p)
                while ((wsp[p] & 0x00010001u) != 0x00010001u) {
                    __builtin_amdgcn_s_sleep(1);
                    wsp[p] = LD_AGENT(hp + (p << 6));
                }
#pragma unroll
            for (int p = 0; p < 8; ++p) {
                f16 h0 = __builtin_bit_cast(f16, (uint16_t)(wsp[p] & 0xFFFFu));
                f16 h1 = __builtin_bit_cast(f16, (uint16_t)(wsp[p] >> 16));
                qf[2 * p][hTq_n + u] = h0;           qf[2 * p + 1][hTq_n + u] = h1;
                qs32[2 * p][hT32_n + u] = (float)h0; qs32[2 * p + 1][hT32_n + u] = (float)h1;
            }
        }
        __syncthreads();   // s2 — rf, Gt ready (and hT(j+1) staged)

        // ---- [C] ----
        if (g >= 4) {
            // wave 7: issue speculative loads for cell j+2 (max latency slack)
            if (g == 7 && row > 0 && j < LDIM - 2) {
                const uint32_t* hp = hbuf + (((size_t)((row - 1) * LDIM + (j + 2)) * NBT + bt) << 9) + u;
#pragma unroll
                for (int p = 0; p < 8; ++p) wsp[p] = LD_AGENT(hp + (p << 6));
            }
            // GEMM2 full K, 2 accumulator chains
            f32x4 a0 = (f32x4){bias2, bias2, bias2, bias2};
            f32x4 a1 = (f32x4){0.f, 0.f, 0.f, 0.f};
#pragma unroll
            for (int s = 0; s < 6; ++s) {
                f16x8 a = *(const f16x8*)&rf[l15][s * 32 + lq * 8];
                if (s & 1) a1 = __builtin_amdgcn_mfma_f32_16x16x32_f16(a, wreg2[s], a1, 0, 0, 0);
                else       a0 = __builtin_amdgcn_mfma_f32_16x16x32_f16(a, wreg2[s], a0, 0, 0, 0);
            }
#pragma unroll
            for (int s = 6; s < 8; ++s) {
                f16x8 a = *(const f16x8*)&qf[l15][sq + (s - 6) * 32 + lq * 8];
                if (s & 1) a1 = __builtin_amdgcn_mfma_f32_16x16x32_f16(a, wreg2[s], a1, 0, 0, 0);
                else       a0 = __builtin_amdgcn_mfma_f32_16x16x32_f16(a, wreg2[s], a0, 0, 0, 0);
            }
            // epilogue: lane owns batches 4lq..4lq+3 at col n2
            uint32_t pk0 = 0u, pk1 = 0u;
#pragma unroll
            for (int r = 0; r < 4; ++r) {
                const int b = lq * 4 + r;
                float hh = a0[r] + a1[r];
                float e2 = __expf(2.f * hh);
                float th = 1.f - 2.f / (e2 + 1.f);               // tanh
                float zi = Gt[n2][b],       zl = Gt[64 + n2][b];
                float zt = Gt[128 + n2][b], zd = Gt[192 + n2][b];
                float mx = fmaxf(fmaxf(zi, zl), fmaxf(zt, zd));
                float ei = __expf(zi - mx), el = __expf(zl - mx);
                float et = __expf(zt - mx), ed = __expf(zd - mx);
                float inv = 1.f / (ei + el + et + ed);
                float hT = qs32[b][hT32 + n2], hL = qs32[b][64 + n2], hD = qs32[b][128 + n2];
                float hv = (el * hL + et * hT + ed * hD + ei * th) * inv;
                // rotate own slots: hD <- hT, hL <- h_new
                qs32[b][128 + n2] = hT;   qs32[b][64 + n2] = hv;
                qf[b][128 + n2] = (f16)hT; qf[b][64 + n2] = (f16)hv;
                if (row == LDIM - 1 && j == LDIM - 1)
                    out[(size_t)(b0 + b) * 64 + n2] = hv;
                uint32_t h16 = (uint32_t)(__builtin_bit_cast(uint16_t, (f16)hv) | 1u);
                if (r & 2) pk1 |= h16 << ((r & 1) * 16);
                else       pk0 |= h16 << ((r & 1) * 16);
            }
            // handoff: pairs 2lq (batches 4lq,4lq+1) and 2lq+1 at unit n2
            uint32_t* dst = hbuf + (((size_t)(row * LDIM + j) * NBT + bt) << 9) + n2;
            ST_AGENT(dst + ((2 * lq) << 6),     pk0);
            ST_AGENT(dst + ((2 * lq + 1) << 6), pk1);
        } else {
            // waves 0-3: stage x(j+1) from regs; prefetch x(j+2)
            if (j < LDIM - 1) {
#pragma unroll
                for (int i = 0; i < 4; ++i)
                    qf[g + 4 * i][sq_n + u] = (f16)xv[i];
                if (j < LDIM - 2) {
#pragma unroll
                    for (int i = 0; i < 4; ++i)
                        xv[i] = xg[(size_t)i * 4 * 65536 + j + 2];
                }
            }
        }
        // loop-top s1 doubles as the post-[C] barrier
    }
}

extern "C" void kernel_launch(void* const* d_in, const int* in_sizes, int n_in,
                              void* d_out, int out_size, void* d_ws, size_t ws_size,
                              hipStream_t stream) {
    const float* x    = (const float*)d_in[0];
    const float* W    = (const float*)d_in[1];
    const float* Urec = (const float*)d_in[2];
    const float* bias = (const float*)d_in[3];
    const float* Wij  = (const float*)d_in[4];
    float* out = (float*)d_out;

    // hbuf: 32*32*4*512 dwords = 8 MB; 0xAAAAAAAA poison fails LSB validity.
    uint32_t* hbuf = (uint32_t*)d_ws;

    spatial_gru_kernel<<<LDIM * NBT, TPB, 0, stream>>>(
        x, W, Urec, bias, Wij, out, hbuf);
}

// Round 9
// 270.723 us; speedup vs baseline: 1.2659x; 1.2659x over previous
//
#include <hip/hip_runtime.h>
#include <cstdint>
#include <cstddef>

// ---------------------------------------------------------------------------
// SpatialGRU 32x32, B=64, U=64, C=64. Persistent: 32 rows x 4 batch-tiles
// (bid=row*4+bt). Flag-free handoff (packed 2xf16 dword, LSB=1 validity).
// R9: software-pipelined cell, 3 barriers:
//  P2(j): waves0-6 FINISH GEMM1(j) (hT,hL k-slices; acc carried from P3(j-1))
//         + sigmoid->rf (w0-2) / z->Gsz (w3-6); wave7 GEMM2 s-slice.
//  P3(j): waves0-6 PRECOMPUTE GEMM1(j+1) (hD=hT(j), s slices);
//         wave7 GEMM2 full-K rest (rf) -> hhat logits to LDS.
//  P1(j): all waves: combine -> h(j); handoff store (b,b+8 packed dword);
//         x(j+2) staging; per-wave poll+stage hT(j+1) (latest phase -> row
//         skew stays C+L; R8's early staging doubled skew and regressed).
// qs32 hT rotates mod-3 (j-1, j, j+1 alive); qf hT/s rotate by parity.
// ---------------------------------------------------------------------------

#define LDIM   32
#define NBT    4
#define BT     16
#define TPB    512

typedef _Float16 f16;
typedef _Float16 f16x8 __attribute__((ext_vector_type(8)));
typedef float    f32x4 __attribute__((ext_vector_type(4)));

#define LD_AGENT(p)   __hip_atomic_load((p), __ATOMIC_RELAXED, __HIP_MEMORY_SCOPE_AGENT)
#define ST_AGENT(p,v) __hip_atomic_store((p), (v), __ATOMIC_RELAXED, __HIP_MEMORY_SCOPE_AGENT)

__global__ __launch_bounds__(TPB, 2) void spatial_gru_kernel(
    const float* __restrict__ x,     // (B, C, 32, 32)
    const float* __restrict__ W,     // (256, 448)
    const float* __restrict__ Urec,  // (192, 64)
    const float* __restrict__ bias,  // (512,)
    const float* __restrict__ Wij,   // (64, 64)
    float* __restrict__ out,         // (B, U)
    uint32_t* __restrict__ hbuf)     // (32,32,NBT)[d 0:8][u 0:64]: batches (d,d+8)
{
    const int bid = blockIdx.x;
    const int row = bid >> 2, bt = bid & 3, b0 = bt * BT;
    const int t = (int)threadIdx.x, u = t & 63, g = t >> 6;
    const int l15 = t & 15, lq = (t & 63) >> 4;

    // ---- LDS ----
    // qf  : A-layout f16 [b][k]: hT0 @0 | hT1 @64 | hL @128 | s0 @192 | s1 @256
    //       (hT slot par(j); s slot par(j); hD(j) == hT slot par(j-1))
    // rf  : GEMM2 A f16 [b][0:192] = r*{hL,hT,hD}
    // qs32: fp32 [b][c]: hT mod-3 slots @0,64,128 | hL @192
    // Gsz : z logits fp32 [b][0:256]
    // hh  : hhat logits fp32 [b][u]
    __shared__ __attribute__((aligned(16))) f16 qf[BT][328];
    __shared__ __attribute__((aligned(16))) f16 rf[BT][200];
    __shared__ float qs32[BT][260];
    __shared__ float Gsz [BT][260];
    __shared__ float hh  [BT][68];

    // ---- weights resident: waves 0-6 = W cols g*64+T*16+l15 (k-blocks s=0..7)
    //      wave 7 = [Urec;Wij] cols T*16+l15 ----
    f16x8 wreg[4][8];
    float bias1[4];
    if (g < 7) {
        const int nb = g * 64 + l15;
#pragma unroll
        for (int T = 0; T < 4; ++T) {
            bias1[T] = bias[nb + 16 * T];
#pragma unroll
            for (int s = 0; s < 8; ++s) {
                f16x8 v;
#pragma unroll
                for (int jj = 0; jj < 8; ++jj) {
                    int kk = s * 32 + lq * 8 + jj;
                    v[jj] = (f16)W[(size_t)kk * 448 + nb + 16 * T];
                }
                wreg[T][s] = v;
            }
        }
    } else {
#pragma unroll
        for (int T = 0; T < 4; ++T) {
            const int nn = T * 16 + l15;
            bias1[T] = bias[448 + nn];
#pragma unroll
            for (int s = 0; s < 8; ++s) {
                f16x8 v;
#pragma unroll
                for (int jj = 0; jj < 8; ++jj) {
                    int kk = s * 32 + lq * 8 + jj;
                    float wv = (kk < 192) ? Urec[kk * 64 + nn] : Wij[(kk - 192) * 64 + nn];
                    v[jj] = (f16)wv;
                }
                wreg[T][s] = v;
            }
        }
    }

    // ---- zero init: qs32[0:256], qf[0:192] ----
    for (int idx = t; idx < 256 * BT; idx += TPB) {
        int b = idx & 15, k = idx >> 4;
        qs32[b][k] = 0.f;
        if (k < 192) qf[b][k] = (f16)0.f;
    }

    // ---- prologue: stage s(0)->@192, s(1)->@256, x(2)->regs, hT(0) ----
    const float* xg0 = x + (size_t)(b0 + g) * 65536 + (size_t)u * 1024 + (size_t)row * 32;
    const float* xg1 = xg0 + (size_t)8 * 65536;
    qf[g][192 + u]     = (f16)xg0[0];  qf[g + 8][192 + u] = (f16)xg1[0];
    qf[g][256 + u]     = (f16)xg0[1];  qf[g + 8][256 + u] = (f16)xg1[1];
    float xv0 = xg0[2], xv1 = xg1[2];
    if (row > 0) {
        const uint32_t* sp = hbuf + (((size_t)((row - 1) * LDIM) * NBT + bt) << 9) + (g << 6) + u;
        uint32_t w = LD_AGENT(sp);
        while ((w & 0x00010001u) != 0x00010001u) {
            __builtin_amdgcn_s_sleep(1);
            w = LD_AGENT(sp);
        }
        f16 h0 = __builtin_bit_cast(f16, (uint16_t)(w & 0xFFFFu));
        f16 h1 = __builtin_bit_cast(f16, (uint16_t)(w >> 16));
        qf[g][u] = h0;            qf[g + 8][u] = h1;          // hT slot 0 (par(0)=0)
        qs32[g][u] = (float)h0;   qs32[g + 8][u] = (float)h1; // mod-3 slot 0
    }
    __syncthreads();

    // ---- prologue precompute cell 0 (waves 0-6): bias + hD(0)(slot@64, zeros)
    //      + s(0)(@192) ----
    f32x4 acc[4];
    if (g < 7) {
#pragma unroll
        for (int T = 0; T < 4; ++T)
            acc[T] = (f32x4){bias1[T], bias1[T], bias1[T], bias1[T]};
#pragma unroll
        for (int sv = 0; sv < 2; ++sv) {
            f16x8 a4 = *(const f16x8*)&qf[l15][64 + sv * 32 + lq * 8];   // hD(0)=0
            f16x8 a6 = *(const f16x8*)&qf[l15][192 + sv * 32 + lq * 8];  // s(0)
#pragma unroll
            for (int T = 0; T < 4; ++T) {
                acc[T] = __builtin_amdgcn_mfma_f32_16x16x32_f16(a4, wreg[T][4 + sv], acc[T], 0, 0, 0);
                acc[T] = __builtin_amdgcn_mfma_f32_16x16x32_f16(a6, wreg[T][6 + sv], acc[T], 0, 0, 0);
            }
        }
    }

    for (int j = 0; j < LDIM; ++j) {
        const int par  = j & 1;
        const int hTq  = par << 6;            // qf hT slot, cell j
        const int hTqn = (1 - par) << 6;      // qf hT slot, cell j+1
        const int sq   = 192 + (par << 6);    // qf s slot, cell j
        const int sqn  = 192 + ((1 - par) << 6);
        const int s3   = (j % 3) * 64;        // qs32 hT(j)
        const int s3p  = ((j + 2) % 3) * 64;  // qs32 hT(j-1) = hD(j)
        const int s3n  = ((j + 1) % 3) * 64;  // qs32 hT(j+1)

        // ---- P2(j): finish GEMM1(j) + sigma/z  |  wave7: GEMM2 s-slice ----
        if (g < 7) {
#pragma unroll
            for (int sv = 0; sv < 2; ++sv) {
                f16x8 a0 = *(const f16x8*)&qf[l15][hTq + sv * 32 + lq * 8];  // hT(j)
                f16x8 a2 = *(const f16x8*)&qf[l15][128 + sv * 32 + lq * 8];  // hL(j)
#pragma unroll
                for (int T = 0; T < 4; ++T) {
                    acc[T] = __builtin_amdgcn_mfma_f32_16x16x32_f16(a0, wreg[T][0 + sv], acc[T], 0, 0, 0);
                    acc[T] = __builtin_amdgcn_mfma_f32_16x16x32_f16(a2, wreg[T][2 + sv], acc[T], 0, 0, 0);
                }
            }
            if (g < 3) {
                // g0: r*hL (@192) | g1: r*hT (slot s3) | g2: r*hD (slot s3p)
                const int colbase = (g == 0) ? 192 : (g == 1) ? s3 : s3p;
#pragma unroll
                for (int T = 0; T < 4; ++T)
#pragma unroll
                    for (int r = 0; r < 4; ++r) {
                        float rr = 1.f / (1.f + __expf(-acc[T][r]));
                        int b = lq * 4 + r;
                        rf[b][g * 64 + T * 16 + l15] = (f16)(rr * qs32[b][colbase + T * 16 + l15]);
                    }
            } else {
                const int zb = (g - 3) * 64;
#pragma unroll
                for (int T = 0; T < 4; ++T)
#pragma unroll
                    for (int r = 0; r < 4; ++r)
                        Gsz[lq * 4 + r][zb + T * 16 + l15] = acc[T][r];
            }
        } else {
#pragma unroll
            for (int T = 0; T < 4; ++T)
                acc[T] = (f32x4){bias1[T], bias1[T], bias1[T], bias1[T]};
#pragma unroll
            for (int sv = 0; sv < 2; ++sv) {
                f16x8 a = *(const f16x8*)&qf[l15][sq + sv * 32 + lq * 8];   // s(j)
#pragma unroll
                for (int T = 0; T < 4; ++T)
                    acc[T] = __builtin_amdgcn_mfma_f32_16x16x32_f16(a, wreg[T][6 + sv], acc[T], 0, 0, 0);
            }
        }
        __syncthreads();   // s2

        // ---- P3(j): precompute GEMM1(j+1) | wave7: GEMM2 rf-part + hh ----
        if (g < 7) {
            if (j < LDIM - 1) {
#pragma unroll
                for (int T = 0; T < 4; ++T)
                    acc[T] = (f32x4){bias1[T], bias1[T], bias1[T], bias1[T]};
#pragma unroll
                for (int sv = 0; sv < 2; ++sv) {
                    f16x8 a4 = *(const f16x8*)&qf[l15][hTq + sv * 32 + lq * 8]; // hD(j+1)=hT(j)
                    f16x8 a6 = *(const f16x8*)&qf[l15][sqn + sv * 32 + lq * 8]; // s(j+1)
#pragma unroll
                    for (int T = 0; T < 4; ++T) {
                        acc[T] = __builtin_amdgcn_mfma_f32_16x16x32_f16(a4, wreg[T][4 + sv], acc[T], 0, 0, 0);
                        acc[T] = __builtin_amdgcn_mfma_f32_16x16x32_f16(a6, wreg[T][6 + sv], acc[T], 0, 0, 0);
                    }
                }
            }
        } else {
#pragma unroll
            for (int s = 0; s < 6; ++s) {
                f16x8 a = *(const f16x8*)&rf[l15][s * 32 + lq * 8];
#pragma unroll
                for (int T = 0; T < 4; ++T)
                    acc[T] = __builtin_amdgcn_mfma_f32_16x16x32_f16(a, wreg[T][s], acc[T], 0, 0, 0);
            }
#pragma unroll
            for (int T = 0; T < 4; ++T)
#pragma unroll
                for (int r = 0; r < 4; ++r)
                    hh[lq * 4 + r][T * 16 + l15] = acc[T][r];
        }
        __syncthreads();   // s3

        // ---- P1(j): combine + handoff + x(j+2) staging + poll hT(j+1) ----
        float hvv[2];
#pragma unroll
        for (int i = 0; i < 2; ++i) {
            const int b = g + 8 * i;
            float hl = hh[b][u];
            float e2 = __expf(2.f * hl);
            float th = 1.f - 2.f / (e2 + 1.f);                 // tanh
            float zi = Gsz[b][u],       zl = Gsz[b][64 + u];
            float zt = Gsz[b][128 + u], zd = Gsz[b][192 + u];
            float mx = fmaxf(fmaxf(zi, zl), fmaxf(zt, zd));
            float ei = __expf(zi - mx), el = __expf(zl - mx);
            float et = __expf(zt - mx), ed = __expf(zd - mx);
            float inv = 1.f / (ei + el + et + ed);
            float hT = qs32[b][s3 + u], hL = qs32[b][192 + u], hD = qs32[b][s3p + u];
            float hv = (el * hL + et * hT + ed * hD + ei * th) * inv;
            hvv[i] = hv;
            qs32[b][192 + u] = hv;          // hL <- h(j)
            qf[b][128 + u]   = (f16)hv;
        }
        if (row < LDIM - 1) {
            uint32_t lo = (uint32_t)(__builtin_bit_cast(uint16_t, (f16)hvv[0]) | 1u);
            uint32_t hi = (uint32_t)(__builtin_bit_cast(uint16_t, (f16)hvv[1]) | 1u);
            ST_AGENT(hbuf + (((size_t)(row * LDIM + j) * NBT + bt) << 9) + (g << 6) + u,
                     (hi << 16) | lo);
        }
        if (row == LDIM - 1 && j == LDIM - 1) {
            out[(size_t)(b0 + g) * 64 + u]     = hvv[0];
            out[(size_t)(b0 + g + 8) * 64 + u] = hvv[1];
        }
        if (j < LDIM - 2) {
            qf[g][sq + u]     = (f16)xv0;   // x(j+2) -> s slot par(j+2)=par(j)
            qf[g + 8][sq + u] = (f16)xv1;
            if (j < LDIM - 3) { xv0 = xg0[j + 3]; xv1 = xg1[j + 3]; }
        }
        if (row > 0 && j < LDIM - 1) {
            const uint32_t* sp =
                hbuf + (((size_t)((row - 1) * LDIM + j + 1) * NBT + bt) << 9) + (g << 6) + u;
            uint32_t w = LD_AGENT(sp);
            while ((w & 0x00010001u) != 0x00010001u) {
                __builtin_amdgcn_s_sleep(1);
                w = LD_AGENT(sp);
            }
            f16 h0 = __builtin_bit_cast(f16, (uint16_t)(w & 0xFFFFu));
            f16 h1 = __builtin_bit_cast(f16, (uint16_t)(w >> 16));
            qf[g][hTqn + u] = h0;          qf[g + 8][hTqn + u] = h1;
            qs32[g][s3n + u] = (float)h0;  qs32[g + 8][s3n + u] = (float)h1;
        }
        __syncthreads();   // s1
    }
}

extern "C" void kernel_launch(void* const* d_in, const int* in_sizes, int n_in,
                              void* d_out, int out_size, void* d_ws, size_t ws_size,
                              hipStream_t stream) {
    const float* x    = (const float*)d_in[0];
    const float* W    = (const float*)d_in[1];
    const float* Urec = (const float*)d_in[2];
    const float* bias = (const float*)d_in[3];
    const float* Wij  = (const float*)d_in[4];
    float* out = (float*)d_out;

    // hbuf: 32*32*4*512 dwords = 8 MB; 0xAAAAAAAA poison fails LSB validity.
    uint32_t* hbuf = (uint32_t*)d_ws;

    spatial_gru_kernel<<<LDIM * NBT, TPB, 0, stream>>>(
        x, W, Urec, bias, Wij, out, hbuf);
}